// Round 8
// baseline (911.523 us; speedup 1.0000x reference)
//
#include <hip/hip_runtime.h>
#include <hip/hip_bf16.h>

#define NN    100000
#define MPAD  100096          // 782*128, >= NN; pad rows zeroed/ignored
#define ER_   500000
#define EA_   500000
#define NCH   25              // scan chunks of 4096 (25*4096 >= NN)
#define F_RELU 2

typedef __attribute__((ext_vector_type(8))) _Float16 f16x8;
typedef __attribute__((ext_vector_type(4))) float f32x4;
typedef __attribute__((address_space(3))) uint lds_uint;
typedef const __attribute__((address_space(1))) uint g_uint;

union H8 { uint4 u; _Float16 h[8]; };
union H1 { _Float16 h; ushort u; };

__device__ __forceinline__ ushort f2h(float f) { H1 c; c.h = (_Float16)f; return c.u; }

// ---------------------------------------------------------------------------
// CSR build: fused count / fill, parallel 3-kernel exclusive scan
// ---------------------------------------------------------------------------
__global__ void count3(const int* __restrict__ dst_rev, const int* __restrict__ dst_ab,
                       const int* __restrict__ src_rev, int* __restrict__ cnt /*3*NN*/) {
    int i = blockIdx.x * blockDim.x + threadIdx.x;
    if (i < ER_)                 atomicAdd(&cnt[dst_rev[i]], 1);
    else if (i < ER_ + EA_)      atomicAdd(&cnt[NN + dst_ab[i - ER_]], 1);
    else if (i < ER_ + EA_ + ER_) atomicAdd(&cnt[2 * NN + src_rev[i - ER_ - EA_]], 1);
}

__global__ void fill3(const int* __restrict__ dst_rev, const int* __restrict__ src_rev,
                      const int* __restrict__ dst_ab, const int* __restrict__ src_ab,
                      const int* __restrict__ pA, const int* __restrict__ pB,
                      const int* __restrict__ pC, int* __restrict__ cur /*3*NN*/,
                      int* __restrict__ colA, int* __restrict__ colB, int* __restrict__ colC) {
    int i = blockIdx.x * blockDim.x + threadIdx.x;
    if (i < ER_) {
        int d = dst_rev[i];
        colA[pA[d] + atomicAdd(&cur[d], 1)] = src_rev[i];
    } else if (i < ER_ + EA_) {
        int e = i - ER_, d = dst_ab[e];
        colB[pB[d] + atomicAdd(&cur[NN + d], 1)] = src_ab[e];
    } else if (i < ER_ + EA_ + ER_) {
        int e = i - ER_ - EA_, d = src_rev[e];
        colC[pC[d] + atomicAdd(&cur[2 * NN + d], 1)] = dst_rev[e];
    }
}

// per-chunk sums: grid 3*NCH blocks
__global__ void scan_part(const int* __restrict__ cnt /*3*NN*/, int* __restrict__ part) {
    int b = blockIdx.x, a = b / NCH, c = b % NCH;
    const int* src = cnt + a * NN;
    int base = c * 4096 + threadIdx.x * 16;
    int s = 0;
    #pragma unroll
    for (int k = 0; k < 16; k += 4) {
        int i = base + k;
        if (i + 3 < NN) { int4 v = *(const int4*)(src + i); s += v.x + v.y + v.z + v.w; }
        else { for (int j = 0; j < 4; j++) if (i + j < NN) s += src[i + j]; }
    }
    __shared__ int ws[4];
    int lane = threadIdx.x & 63, wid = threadIdx.x >> 6;
    #pragma unroll
    for (int o = 32; o > 0; o >>= 1) s += __shfl_down(s, o, 64);
    if (lane == 0) ws[wid] = s;
    __syncthreads();
    if (threadIdx.x == 0) part[b] = ws[0] + ws[1] + ws[2] + ws[3];
}

// chunk offsets + totals: 1 block
__global__ void scan_off(const int* __restrict__ part, int* __restrict__ choff,
                         int* __restrict__ pA, int* __restrict__ pB, int* __restrict__ pC) {
    int a = threadIdx.x;
    if (a < 3) {
        int acc = 0;
        for (int c = 0; c < NCH; c++) { choff[a * NCH + c] = acc; acc += part[a * NCH + c]; }
        int* p = (a == 0) ? pA : (a == 1) ? pB : pC;
        p[NN] = acc;
    }
}

// apply: grid 3*NCH blocks; exclusive scan within chunk + chunk offset
__global__ void scan_apply(const int* __restrict__ cnt, const int* __restrict__ choff,
                           int* __restrict__ pA, int* __restrict__ pB, int* __restrict__ pC) {
    int b = blockIdx.x, a = b / NCH, c = b % NCH;
    const int* src = cnt + a * NN;
    int* ptr = (a == 0) ? pA : (a == 1) ? pB : pC;
    int tid = threadIdx.x, lane = tid & 63, wid = tid >> 6;
    int base = c * 4096 + tid * 16;
    int v[16], s = 0;
    #pragma unroll
    for (int k = 0; k < 16; k++) { int i = base + k; v[k] = (i < NN) ? src[i] : 0; s += v[k]; }
    int isc = s;
    #pragma unroll
    for (int o = 1; o < 64; o <<= 1) { int t = __shfl_up(isc, o, 64); if (lane >= o) isc += t; }
    __shared__ int wsum[4];
    if (lane == 63) wsum[wid] = isc;
    __syncthreads();
    int woff = 0;
    for (int wj = 0; wj < wid; wj++) woff += wsum[wj];
    int excl = choff[a * NCH + c] + woff + (isc - s);
    #pragma unroll
    for (int k = 0; k < 16; k++) { int i = base + k; if (i < NN) ptr[i] = excl; excl += v[k]; }
}

// ---------------------------------------------------------------------------
// Fused prep: cvt x_user/x_item fp32->fp16 planes + 10 weight transposes
// ---------------------------------------------------------------------------
struct PrepArgs {
    const float* xsrc[2]; ushort* xdst[2];
    const float* W0[10]; const float* W1[10]; ushort* T[10];
};

__global__ void prep_all(PrepArgs A) {
    const long CVB = (long)MPAD * 128 / 8 / 256;   // 6256 blocks per cvt
    long b = blockIdx.x;
    if (b < 2 * CVB) {
        int which = (b >= CVB);
        long lb = b - which * CVB;
        long i = (lb * 256 + threadIdx.x) * 8;
        const float* x = A.xsrc[which];
        ushort* o = A.xdst[which];
        float4 v0 = {0.f,0.f,0.f,0.f}, v1 = {0.f,0.f,0.f,0.f};
        if (i < (long)NN * 128) { v0 = *(const float4*)(x + i); v1 = *(const float4*)(x + i + 4); }
        H8 r;
        r.h[0]=(_Float16)v0.x; r.h[1]=(_Float16)v0.y; r.h[2]=(_Float16)v0.z; r.h[3]=(_Float16)v0.w;
        r.h[4]=(_Float16)v1.x; r.h[5]=(_Float16)v1.y; r.h[6]=(_Float16)v1.z; r.h[7]=(_Float16)v1.w;
        *(uint4*)(o + i) = r.u;
        return;
    }
    long j = (b - 2 * CVB) * 256 + threadIdx.x;    // 0 .. 491519
    int idx, rem, K;
    if (j < 5 * 32768) { idx = j >> 15; rem = j & 32767; K = 128; }
    else {
        long j2 = j - 5 * 32768;
        if (j2 >= 5L * 65536) return;
        idx = 5 + (int)(j2 >> 16); rem = (int)(j2 & 65535); K = 256;
    }
    int k = rem >> 8, n = rem & 255;
    float v = A.W0[idx][rem];
    if (A.W1[idx]) v += A.W1[idx][rem];
    A.T[idx][n * K + k] = f2h(v);
}

// ---------------------------------------------------------------------------
// Fused aggregations: 3 directions x 2 column-halves per dispatch.
// Half-D split halves bytes-per-row in L2 (doubles row density -> hit rate);
// 4x edge unroll issues 4 independent row loads (MLP). Mean, pad rows -> 0.
// ---------------------------------------------------------------------------
__global__ void agg3_128(const ushort* __restrict__ xu, const ushort* __restrict__ xi,
                         const int* __restrict__ pA, const int* __restrict__ cA,
                         const int* __restrict__ pB, const int* __restrict__ cB,
                         const int* __restrict__ pC, const int* __restrict__ cC,
                         ushort* __restrict__ sA, ushort* __restrict__ sB,
                         ushort* __restrict__ sC) {
    const int SEG = MPAD * 8 / 256;    // 3128 blocks per segment (8 lanes/half-row)
    int seg = blockIdx.x / SEG, lb = blockIdx.x % SEG;
    int dir = seg % 3, half = seg / 3;
    const ushort* x; const int* ptr; const int* col; ushort* out;
    if (dir == 0)      { x = xu; ptr = pA; col = cA; out = sA; }
    else if (dir == 1) { x = xi; ptr = pB; col = cB; out = sB; }
    else               { x = xi; ptr = pC; col = cC; out = sC; }
    int g = lb * 256 + threadIdx.x;
    int node = g >> 3, l = g & 7;
    if (node >= MPAD) return;
    int doff = half * 64 + l * 8;
    size_t ob = (size_t)node * 128 + doff;
    if (node >= NN) { *(uint4*)(out + ob) = make_uint4(0,0,0,0); return; }
    const ushort* xb = x + doff;
    int p0 = ptr[node], p1 = ptr[node + 1];
    float a[8] = {0.f,0.f,0.f,0.f,0.f,0.f,0.f,0.f};
    int e = p0;
    for (; e + 4 <= p1; e += 4) {
        int c0 = col[e], c1 = col[e+1], c2 = col[e+2], c3 = col[e+3];
        H8 v0, v1, v2, v3;
        v0.u = *(const uint4*)(xb + (size_t)c0 * 128);
        v1.u = *(const uint4*)(xb + (size_t)c1 * 128);
        v2.u = *(const uint4*)(xb + (size_t)c2 * 128);
        v3.u = *(const uint4*)(xb + (size_t)c3 * 128);
        #pragma unroll
        for (int k = 0; k < 8; k++) a[k] += (float)v0.h[k];
        #pragma unroll
        for (int k = 0; k < 8; k++) a[k] += (float)v1.h[k];
        #pragma unroll
        for (int k = 0; k < 8; k++) a[k] += (float)v2.h[k];
        #pragma unroll
        for (int k = 0; k < 8; k++) a[k] += (float)v3.h[k];
    }
    for (; e < p1; ++e) {
        H8 v; v.u = *(const uint4*)(xb + (size_t)col[e] * 128);
        #pragma unroll
        for (int k = 0; k < 8; k++) a[k] += (float)v.h[k];
    }
    float inv = (p1 > p0) ? 1.0f / (float)(p1 - p0) : 0.0f;
    H8 r;
    #pragma unroll
    for (int k = 0; k < 8; k++) r.h[k] = (_Float16)(a[k] * inv);
    *(uint4*)(out + ob) = r.u;
}

__global__ void agg3_256(const ushort* __restrict__ hU, const ushort* __restrict__ hI,
                         const int* __restrict__ pA, const int* __restrict__ cA,
                         const int* __restrict__ pB, const int* __restrict__ cB,
                         const int* __restrict__ pC, const int* __restrict__ cC,
                         ushort* __restrict__ sA, ushort* __restrict__ sB,
                         ushort* __restrict__ sC) {
    const int SEG = MPAD * 16 / 256;   // 6256 blocks per segment (16 lanes/half-row)
    int seg = blockIdx.x / SEG, lb = blockIdx.x % SEG;
    int dir = seg % 3, half = seg / 3;
    const ushort* x; const int* ptr; const int* col; ushort* out;
    if (dir == 0)      { x = hU; ptr = pA; col = cA; out = sA; }
    else if (dir == 1) { x = hI; ptr = pB; col = cB; out = sB; }
    else               { x = hI; ptr = pC; col = cC; out = sC; }
    int g = lb * 256 + threadIdx.x;
    int node = g >> 4, l = g & 15;
    if (node >= MPAD) return;
    int doff = half * 128 + l * 8;
    size_t ob = (size_t)node * 256 + doff;
    if (node >= NN) { *(uint4*)(out + ob) = make_uint4(0,0,0,0); return; }
    const ushort* xb = x + doff;
    int p0 = ptr[node], p1 = ptr[node + 1];
    float a[8] = {0.f,0.f,0.f,0.f,0.f,0.f,0.f,0.f};
    int e = p0;
    for (; e + 4 <= p1; e += 4) {
        int c0 = col[e], c1 = col[e+1], c2 = col[e+2], c3 = col[e+3];
        H8 v0, v1, v2, v3;
        v0.u = *(const uint4*)(xb + (size_t)c0 * 256);
        v1.u = *(const uint4*)(xb + (size_t)c1 * 256);
        v2.u = *(const uint4*)(xb + (size_t)c2 * 256);
        v3.u = *(const uint4*)(xb + (size_t)c3 * 256);
        #pragma unroll
        for (int k = 0; k < 8; k++) a[k] += (float)v0.h[k];
        #pragma unroll
        for (int k = 0; k < 8; k++) a[k] += (float)v1.h[k];
        #pragma unroll
        for (int k = 0; k < 8; k++) a[k] += (float)v2.h[k];
        #pragma unroll
        for (int k = 0; k < 8; k++) a[k] += (float)v3.h[k];
    }
    for (; e < p1; ++e) {
        H8 v; v.u = *(const uint4*)(xb + (size_t)col[e] * 256);
        #pragma unroll
        for (int k = 0; k < 8; k++) a[k] += (float)v.h[k];
    }
    float inv = (p1 > p0) ? 1.0f / (float)(p1 - p0) : 0.0f;
    H8 r;
    #pragma unroll
    for (int k = 0; k < 8; k++) r.h[k] = (_Float16)(a[k] * inv);
    *(uint4*)(out + ob) = r.u;
}

// ---------------------------------------------------------------------------
// fp16 MFMA GEMM, up to 3 fused parts, 2 problems per dispatch (blockIdx.z).
// 2-phase double-buffered: ONE barrier per K-step; stage(t+1) issued after
// the barrier, drained at the NEXT barrier -> staging overlaps 32 MFMA.
// ---------------------------------------------------------------------------
struct GP {
    const ushort *A0, *W0, *A1, *W1, *A2, *W2;
    int ksh0, ksh1, ksh2;
    int c1, c2, S;
};

__global__ __launch_bounds__(256)
void gemm2x(GP Pa, const float* b0a, const float* b1a, float* Cfa, ushort* Cha, int fla,
            GP Pb, const float* b0b, const float* b1b, float* Cfb, ushort* Chb, int flb) {
    GP P; const float *b0, *b1; float* Cf; ushort* Ch; int flags;
    if (blockIdx.z == 0) { P = Pa; b0 = b0a; b1 = b1a; Cf = Cfa; Ch = Cha; flags = fla; }
    else                 { P = Pb; b0 = b0b; b1 = b1b; Cf = Cfb; Ch = Chb; flags = flb; }

    __shared__ ushort sA[2][128 * 64];
    __shared__ ushort sW[2][128 * 64];
    const int tid = threadIdx.x;
    const int m0 = blockIdx.x * 128, n0 = blockIdx.y * 128;
    const int lane = tid & 63, w = tid >> 6;
    const int wr = (w >> 1) * 64, wc = (w & 1) * 64;
    const int fcol = lane & 15, fq = lane >> 4;
    const int srow = tid >> 3, sc = tid & 7;

    f32x4 acc[4][4];
    #pragma unroll
    for (int i = 0; i < 4; i++)
        #pragma unroll
        for (int j = 0; j < 4; j++) acc[i][j] = (f32x4){0.f,0.f,0.f,0.f};

    auto stage = [&](int t, int buf) {
        if (t >= P.S) return;   // uniform
        int p = (t >= P.c1) + (t >= P.c2);
        const ushort* A = (p == 2) ? P.A2 : (p == 1) ? P.A1 : P.A0;
        const ushort* W = (p == 2) ? P.W2 : (p == 1) ? P.W1 : P.W0;
        int ksh  = (p == 2) ? P.ksh2 : (p == 1) ? P.ksh1 : P.ksh0;
        int base = (p == 2) ? P.c2 : (p == 1) ? P.c1 : 0;
        int k0 = (t - base) << 6;
        #pragma unroll
        for (int ii = 0; ii < 4; ++ii) {
            int row = ii * 32 + srow;
            int q = sc ^ (row & 7);
            const ushort* srcA = A + (((size_t)(m0 + row)) << ksh) + k0 + q * 8;
            const ushort* srcW = W + (((size_t)(n0 + row)) << ksh) + k0 + q * 8;
            __builtin_amdgcn_global_load_lds((g_uint*)srcA,
                (lds_uint*)(&sA[buf][row * 64 + sc * 8]), 16, 0, 0);
            __builtin_amdgcn_global_load_lds((g_uint*)srcW,
                (lds_uint*)(&sW[buf][row * 64 + sc * 8]), 16, 0, 0);
        }
    };

    stage(0, 0);
    int cur = 0;
    #pragma unroll 1
    for (int t = 0; t < P.S; ++t) {
        __syncthreads();            // drains stage(t) into buf[cur] (vmcnt0+lgkmcnt0)
        stage(t + 1, cur ^ 1);      // in flight across this step's compute
        const ushort* bA = sA[cur];
        const ushort* bW = sW[cur];
        #pragma unroll
        for (int kk = 0; kk < 2; ++kk) {
            f16x8 a[4], b[4];
            #pragma unroll
            for (int i = 0; i < 4; ++i) {
                int ra = wr + i * 16 + fcol;
                int s = (fq + kk * 4) ^ (ra & 7);
                a[i] = *(const f16x8*)(bA + ra * 64 + s * 8);
            }
            #pragma unroll
            for (int j = 0; j < 4; ++j) {
                int rw = wc + j * 16 + fcol;
                int s = (fq + kk * 4) ^ (rw & 7);
                b[j] = *(const f16x8*)(bW + rw * 64 + s * 8);
            }
            #pragma unroll
            for (int i = 0; i < 4; ++i)
                #pragma unroll
                for (int j = 0; j < 4; ++j)
                    acc[i][j] = __builtin_amdgcn_mfma_f32_16x16x32_f16(a[i], b[j], acc[i][j], 0, 0, 0);
        }
        cur ^= 1;
    }

    const bool relu = flags & F_RELU;
    float bb[4];
    #pragma unroll
    for (int j = 0; j < 4; ++j) {
        int cg = n0 + wc + j * 16 + fcol;
        float v = 0.f;
        if (b0) v += b0[cg];
        if (b1) v += b1[cg];
        bb[j] = v;
    }
    #pragma unroll
    for (int i = 0; i < 4; ++i) {
        #pragma unroll
        for (int r = 0; r < 4; ++r) {
            int gm = m0 + wr + i * 16 + fq * 4 + r;
            if (gm >= NN) continue;
            size_t rowb = (size_t)gm * 256;
            #pragma unroll
            for (int j = 0; j < 4; ++j) {
                size_t idx = rowb + n0 + wc + j * 16 + fcol;
                float v = acc[i][j][r] + bb[j];
                if (relu) v = fmaxf(v, 0.f);
                if (Ch) Ch[idx] = f2h(v);
                else    Cf[idx] = v;
            }
        }
    }
}

// ---------------------------------------------------------------------------
extern "C" void kernel_launch(void* const* d_in, const int* in_sizes, int n_in,
                              void* d_out, int out_size, void* d_ws, size_t ws_size,
                              hipStream_t stream) {
    const float* x_user = (const float*)d_in[0];
    const float* x_item = (const float*)d_in[1];
    const int* src_rev  = (const int*)d_in[2];
    const int* dst_rev  = (const int*)d_in[3];
    const int* src_ab   = (const int*)d_in[4];
    const int* dst_ab   = (const int*)d_in[5];
    const float* Wl1_rev  = (const float*)d_in[6];
    const float* Wr1_rev  = (const float*)d_in[7];
    const float* b1_rev   = (const float*)d_in[8];
    const float* Wl1_rrev = (const float*)d_in[9];
    const float* Wr1_rrev = (const float*)d_in[10];
    const float* b1_rrev  = (const float*)d_in[11];
    const float* Wl1_ab   = (const float*)d_in[12];
    const float* Wr1_ab   = (const float*)d_in[13];
    const float* b1_ab    = (const float*)d_in[14];
    const float* Wl2_rev  = (const float*)d_in[15];
    const float* Wr2_rev  = (const float*)d_in[16];
    const float* b2_rev   = (const float*)d_in[17];
    const float* Wl2_rrev = (const float*)d_in[18];
    const float* Wr2_rrev = (const float*)d_in[19];
    const float* b2_rrev  = (const float*)d_in[20];
    const float* Wl2_ab   = (const float*)d_in[21];
    const float* Wr2_ab   = (const float*)d_in[22];
    const float* b2_ab    = (const float*)d_in[23];

    float* o_user = (float*)d_out;
    float* o_item = (float*)d_out + (size_t)NN * 256;

    char* ws = (char*)d_ws;
    size_t off = 0;
    auto alloc = [&](size_t bytes) -> void* {
        void* p = ws + off;
        off += (bytes + 255) & ~(size_t)255;
        return p;
    };
    const size_t P256 = (size_t)MPAD * 256 * 2;
    const size_t P128 = (size_t)MPAD * 128 * 2;
    ushort* xu     = (ushort*)alloc(P128);
    ushort* xi     = (ushort*)alloc(P128);
    ushort* slabA  = (ushort*)alloc(P128);
    ushort* slabB  = (ushort*)alloc(P128);
    ushort* slabC  = (ushort*)alloc(P128);
    ushort* hI     = (ushort*)alloc(P256);
    ushort* hU     = (ushort*)alloc(P256);
    ushort* s2A    = (ushort*)alloc(P256);
    ushort* s2B    = (ushort*)alloc(P256);
    ushort* s2C    = (ushort*)alloc(P256);
    const size_t W1SZ = 128 * 256 * 2, W2SZ = 256 * 256 * 2;
    ushort* wt_l1rev  = (ushort*)alloc(W1SZ);
    ushort* wt_l1ab   = (ushort*)alloc(W1SZ);
    ushort* wt_l1rrev = (ushort*)alloc(W1SZ);
    ushort* wt_r1c    = (ushort*)alloc(W1SZ);
    ushort* wt_r1rrev = (ushort*)alloc(W1SZ);
    ushort* wt_l2rev  = (ushort*)alloc(W2SZ);
    ushort* wt_l2ab   = (ushort*)alloc(W2SZ);
    ushort* wt_l2rrev = (ushort*)alloc(W2SZ);
    ushort* wt_r2c    = (ushort*)alloc(W2SZ);
    ushort* wt_r2rrev = (ushort*)alloc(W2SZ);
    int* ptrA = (int*)alloc((NN + 1) * 4);
    int* ptrB = (int*)alloc((NN + 1) * 4);
    int* ptrC = (int*)alloc((NN + 1) * 4);
    int* colA = (int*)alloc((size_t)ER_ * 4);
    int* colB = (int*)alloc((size_t)EA_ * 4);
    int* colC = (int*)alloc((size_t)ER_ * 4);
    int* cnt3 = (int*)alloc((size_t)3 * NN * 4);   // counts, then reused as cursors
    int* part  = (int*)alloc(3 * NCH * 4);
    int* choff = (int*)alloc(3 * NCH * 4);

    const int TPB = 256;
    const int NE3 = ER_ + EA_ + ER_;
    dim3 e3grid((NE3 + TPB - 1) / TPB);

    // ---- CSR build ----
    hipMemsetAsync(cnt3, 0, (size_t)3 * NN * 4, stream);
    count3<<<e3grid, TPB, 0, stream>>>(dst_rev, dst_ab, src_rev, cnt3);
    scan_part<<<3 * NCH, TPB, 0, stream>>>(cnt3, part);
    scan_off<<<1, 64, 0, stream>>>(part, choff, ptrA, ptrB, ptrC);
    scan_apply<<<3 * NCH, TPB, 0, stream>>>(cnt3, choff, ptrA, ptrB, ptrC);
    hipMemsetAsync(cnt3, 0, (size_t)3 * NN * 4, stream);
    fill3<<<e3grid, TPB, 0, stream>>>(dst_rev, src_rev, dst_ab, src_ab,
                                      ptrA, ptrB, ptrC, cnt3, colA, colB, colC);

    // ---- fused prep (cvt x2 + wprep x10) ----
    PrepArgs PA;
    PA.xsrc[0] = x_user; PA.xdst[0] = xu;
    PA.xsrc[1] = x_item; PA.xdst[1] = xi;
    const float* W0s[10] = {Wl1_rev, Wl1_ab, Wl1_rrev, Wr1_rev, Wr1_rrev,
                            Wl2_rev, Wl2_ab, Wl2_rrev, Wr2_rev, Wr2_rrev};
    const float* W1s[10] = {nullptr, nullptr, nullptr, Wr1_ab, nullptr,
                            nullptr, nullptr, nullptr, Wr2_ab, nullptr};
    ushort* Ts[10] = {wt_l1rev, wt_l1ab, wt_l1rrev, wt_r1c, wt_r1rrev,
                      wt_l2rev, wt_l2ab, wt_l2rrev, wt_r2c, wt_r2rrev};
    for (int i = 0; i < 10; i++) { PA.W0[i] = W0s[i]; PA.W1[i] = W1s[i]; PA.T[i] = Ts[i]; }
    const long CVB = (long)MPAD * 128 / 8 / 256;          // 6256
    const long WPB = (5 * 32768 + 5 * 65536 + 255) / 256; // 1920
    prep_all<<<(int)(2 * CVB + WPB), TPB, 0, stream>>>(PA);

    dim3 ggrid(MPAD / 128, 2, 2);

    auto mkGP = [&](const ushort* a0, const ushort* w0, int K0,
                    const ushort* a1, const ushort* w1, int K1,
                    const ushort* a2, const ushort* w2, int K2) {
        GP P;
        P.A0 = a0; P.W0 = w0;
        P.A1 = a1 ? a1 : a0; P.W1 = w1 ? w1 : w0;
        P.A2 = a2 ? a2 : a0; P.W2 = w2 ? w2 : w0;
        P.ksh0 = (K0 == 256) ? 8 : 7;
        P.ksh1 = (K1 == 256) ? 8 : 7;
        P.ksh2 = (K2 == 256) ? 8 : 7;
        P.c1 = K0 >> 6; P.c2 = P.c1 + (K1 >> 6); P.S = P.c2 + (K2 >> 6);
        return P;
    };

    // ---- layer 1 ----
    agg3_128<<<6 * (MPAD * 8 / 256), TPB, 0, stream>>>(xu, xi, ptrA, colA, ptrB, colB,
                                                       ptrC, colC, slabA, slabB, slabC);
    {
        GP P0 = mkGP(slabA, wt_l1rev, 128, slabB, wt_l1ab, 128, xi, wt_r1c, 128);
        GP P1 = mkGP(slabC, wt_l1rrev, 128, xu, wt_r1rrev, 128, nullptr, nullptr, 0);
        gemm2x<<<ggrid, TPB, 0, stream>>>(P0, b1_rev, b1_ab, nullptr, hI, F_RELU,
                                          P1, b1_rrev, nullptr, nullptr, hU, F_RELU);
    }

    // ---- layer 2 ----
    agg3_256<<<6 * (MPAD * 16 / 256), TPB, 0, stream>>>(hU, hI, ptrA, colA, ptrB, colB,
                                                        ptrC, colC, s2A, s2B, s2C);
    {
        GP P0 = mkGP(s2A, wt_l2rev, 256, s2B, wt_l2ab, 256, hI, wt_r2c, 256);
        GP P1 = mkGP(s2C, wt_l2rrev, 256, hU, wt_r2rrev, 256, nullptr, nullptr, 0);
        gemm2x<<<ggrid, TPB, 0, stream>>>(P0, b2_rev, b2_ab, o_item, nullptr, 0,
                                          P1, b2_rrev, nullptr, o_user, nullptr, 0);
    }
}

// Round 11
// 816.827 us; speedup vs baseline: 1.1159x; 1.1159x over previous
//
#include <hip/hip_runtime.h>
#include <hip/hip_bf16.h>

#define NN    100000
#define MPAD  100096          // 782*128, >= NN; pad rows zeroed/ignored
#define ER_   500000
#define EA_   500000
#define NCH   25              // scan chunks of 4096 (25*4096 >= NN)
#define F_RELU 2

typedef __attribute__((ext_vector_type(8))) _Float16 f16x8;
typedef __attribute__((ext_vector_type(4))) float f32x4;
typedef __attribute__((address_space(3))) uint lds_uint;
typedef const __attribute__((address_space(1))) uint g_uint;

union H8 { uint4 u; _Float16 h[8]; };
union H1 { _Float16 h; ushort u; };

__device__ __forceinline__ ushort f2h(float f) { H1 c; c.h = (_Float16)f; return c.u; }

// ---------------------------------------------------------------------------
// CSR build: fused count / fill, parallel 3-kernel exclusive scan
// ---------------------------------------------------------------------------
__global__ void count3(const int* __restrict__ dst_rev, const int* __restrict__ dst_ab,
                       const int* __restrict__ src_rev, int* __restrict__ cnt /*3*NN*/) {
    int i = blockIdx.x * blockDim.x + threadIdx.x;
    if (i < ER_)                 atomicAdd(&cnt[dst_rev[i]], 1);
    else if (i < ER_ + EA_)      atomicAdd(&cnt[NN + dst_ab[i - ER_]], 1);
    else if (i < ER_ + EA_ + ER_) atomicAdd(&cnt[2 * NN + src_rev[i - ER_ - EA_]], 1);
}

__global__ void fill3(const int* __restrict__ dst_rev, const int* __restrict__ src_rev,
                      const int* __restrict__ dst_ab, const int* __restrict__ src_ab,
                      const int* __restrict__ pA, const int* __restrict__ pB,
                      const int* __restrict__ pC, int* __restrict__ cur /*3*NN*/,
                      int* __restrict__ colA, int* __restrict__ colB, int* __restrict__ colC) {
    int i = blockIdx.x * blockDim.x + threadIdx.x;
    if (i < ER_) {
        int d = dst_rev[i];
        colA[pA[d] + atomicAdd(&cur[d], 1)] = src_rev[i];
    } else if (i < ER_ + EA_) {
        int e = i - ER_, d = dst_ab[e];
        colB[pB[d] + atomicAdd(&cur[NN + d], 1)] = src_ab[e];
    } else if (i < ER_ + EA_ + ER_) {
        int e = i - ER_ - EA_, d = src_rev[e];
        colC[pC[d] + atomicAdd(&cur[2 * NN + d], 1)] = dst_rev[e];
    }
}

// per-chunk sums: grid 3*NCH blocks
__global__ void scan_part(const int* __restrict__ cnt /*3*NN*/, int* __restrict__ part) {
    int b = blockIdx.x, a = b / NCH, c = b % NCH;
    const int* src = cnt + a * NN;
    int base = c * 4096 + threadIdx.x * 16;
    int s = 0;
    #pragma unroll
    for (int k = 0; k < 16; k += 4) {
        int i = base + k;
        if (i + 3 < NN) { int4 v = *(const int4*)(src + i); s += v.x + v.y + v.z + v.w; }
        else { for (int j = 0; j < 4; j++) if (i + j < NN) s += src[i + j]; }
    }
    __shared__ int ws[4];
    int lane = threadIdx.x & 63, wid = threadIdx.x >> 6;
    #pragma unroll
    for (int o = 32; o > 0; o >>= 1) s += __shfl_down(s, o, 64);
    if (lane == 0) ws[wid] = s;
    __syncthreads();
    if (threadIdx.x == 0) part[b] = ws[0] + ws[1] + ws[2] + ws[3];
}

// chunk offsets + totals: 1 block
__global__ void scan_off(const int* __restrict__ part, int* __restrict__ choff,
                         int* __restrict__ pA, int* __restrict__ pB, int* __restrict__ pC) {
    int a = threadIdx.x;
    if (a < 3) {
        int acc = 0;
        for (int c = 0; c < NCH; c++) { choff[a * NCH + c] = acc; acc += part[a * NCH + c]; }
        int* p = (a == 0) ? pA : (a == 1) ? pB : pC;
        p[NN] = acc;
    }
}

// apply: grid 3*NCH blocks; exclusive scan within chunk + chunk offset
__global__ void scan_apply(const int* __restrict__ cnt, const int* __restrict__ choff,
                           int* __restrict__ pA, int* __restrict__ pB, int* __restrict__ pC) {
    int b = blockIdx.x, a = b / NCH, c = b % NCH;
    const int* src = cnt + a * NN;
    int* ptr = (a == 0) ? pA : (a == 1) ? pB : pC;
    int tid = threadIdx.x, lane = tid & 63, wid = tid >> 6;
    int base = c * 4096 + tid * 16;
    int v[16], s = 0;
    #pragma unroll
    for (int k = 0; k < 16; k++) { int i = base + k; v[k] = (i < NN) ? src[i] : 0; s += v[k]; }
    int isc = s;
    #pragma unroll
    for (int o = 1; o < 64; o <<= 1) { int t = __shfl_up(isc, o, 64); if (lane >= o) isc += t; }
    __shared__ int wsum[4];
    if (lane == 63) wsum[wid] = isc;
    __syncthreads();
    int woff = 0;
    for (int wj = 0; wj < wid; wj++) woff += wsum[wj];
    int excl = choff[a * NCH + c] + woff + (isc - s);
    #pragma unroll
    for (int k = 0; k < 16; k++) { int i = base + k; if (i < NN) ptr[i] = excl; excl += v[k]; }
}

// ---------------------------------------------------------------------------
// Fused prep: cvt x_user/x_item fp32->fp16 planes + 10 weight transposes
// ---------------------------------------------------------------------------
struct PrepArgs {
    const float* xsrc[2]; ushort* xdst[2];
    const float* W0[10]; const float* W1[10]; ushort* T[10];
};

__global__ void prep_all(PrepArgs A) {
    const long CVB = (long)MPAD * 128 / 8 / 256;   // 6256 blocks per cvt
    long b = blockIdx.x;
    if (b < 2 * CVB) {
        int which = (b >= CVB);
        long lb = b - which * CVB;
        long i = (lb * 256 + threadIdx.x) * 8;
        const float* x = A.xsrc[which];
        ushort* o = A.xdst[which];
        float4 v0 = {0.f,0.f,0.f,0.f}, v1 = {0.f,0.f,0.f,0.f};
        if (i < (long)NN * 128) { v0 = *(const float4*)(x + i); v1 = *(const float4*)(x + i + 4); }
        H8 r;
        r.h[0]=(_Float16)v0.x; r.h[1]=(_Float16)v0.y; r.h[2]=(_Float16)v0.z; r.h[3]=(_Float16)v0.w;
        r.h[4]=(_Float16)v1.x; r.h[5]=(_Float16)v1.y; r.h[6]=(_Float16)v1.z; r.h[7]=(_Float16)v1.w;
        *(uint4*)(o + i) = r.u;
        return;
    }
    long j = (b - 2 * CVB) * 256 + threadIdx.x;    // 0 .. 491519
    int idx, rem, K;
    if (j < 5 * 32768) { idx = j >> 15; rem = j & 32767; K = 128; }
    else {
        long j2 = j - 5 * 32768;
        if (j2 >= 5L * 65536) return;
        idx = 5 + (int)(j2 >> 16); rem = (int)(j2 & 65535); K = 256;
    }
    int k = rem >> 8, n = rem & 255;
    float v = A.W0[idx][rem];
    if (A.W1[idx]) v += A.W1[idx][rem];
    A.T[idx][n * K + k] = f2h(v);
}

// ---------------------------------------------------------------------------
// Fused aggregations: 3 directions x 2 column-halves per dispatch.
// Half-D split halves bytes-per-row in L2 (doubles row density -> hit rate);
// 4x edge unroll issues 4 independent row loads (MLP). Mean, pad rows -> 0.
// ---------------------------------------------------------------------------
__global__ void agg3_128(const ushort* __restrict__ xu, const ushort* __restrict__ xi,
                         const int* __restrict__ pA, const int* __restrict__ cA,
                         const int* __restrict__ pB, const int* __restrict__ cB,
                         const int* __restrict__ pC, const int* __restrict__ cC,
                         ushort* __restrict__ sA, ushort* __restrict__ sB,
                         ushort* __restrict__ sC) {
    const int SEG = MPAD * 8 / 256;    // 3128 blocks per segment (8 lanes/half-row)
    int seg = blockIdx.x / SEG, lb = blockIdx.x % SEG;
    int dir = seg % 3, half = seg / 3;
    const ushort* x; const int* ptr; const int* col; ushort* out;
    if (dir == 0)      { x = xu; ptr = pA; col = cA; out = sA; }
    else if (dir == 1) { x = xi; ptr = pB; col = cB; out = sB; }
    else               { x = xi; ptr = pC; col = cC; out = sC; }
    int g = lb * 256 + threadIdx.x;
    int node = g >> 3, l = g & 7;
    if (node >= MPAD) return;
    int doff = half * 64 + l * 8;
    size_t ob = (size_t)node * 128 + doff;
    if (node >= NN) { *(uint4*)(out + ob) = make_uint4(0,0,0,0); return; }
    const ushort* xb = x + doff;
    int p0 = ptr[node], p1 = ptr[node + 1];
    float a[8] = {0.f,0.f,0.f,0.f,0.f,0.f,0.f,0.f};
    int e = p0;
    for (; e + 4 <= p1; e += 4) {
        int c0 = col[e], c1 = col[e+1], c2 = col[e+2], c3 = col[e+3];
        H8 v0, v1, v2, v3;
        v0.u = *(const uint4*)(xb + (size_t)c0 * 128);
        v1.u = *(const uint4*)(xb + (size_t)c1 * 128);
        v2.u = *(const uint4*)(xb + (size_t)c2 * 128);
        v3.u = *(const uint4*)(xb + (size_t)c3 * 128);
        #pragma unroll
        for (int k = 0; k < 8; k++) a[k] += (float)v0.h[k];
        #pragma unroll
        for (int k = 0; k < 8; k++) a[k] += (float)v1.h[k];
        #pragma unroll
        for (int k = 0; k < 8; k++) a[k] += (float)v2.h[k];
        #pragma unroll
        for (int k = 0; k < 8; k++) a[k] += (float)v3.h[k];
    }
    for (; e < p1; ++e) {
        H8 v; v.u = *(const uint4*)(xb + (size_t)col[e] * 128);
        #pragma unroll
        for (int k = 0; k < 8; k++) a[k] += (float)v.h[k];
    }
    float inv = (p1 > p0) ? 1.0f / (float)(p1 - p0) : 0.0f;
    H8 r;
    #pragma unroll
    for (int k = 0; k < 8; k++) r.h[k] = (_Float16)(a[k] * inv);
    *(uint4*)(out + ob) = r.u;
}

__global__ void agg3_256(const ushort* __restrict__ hU, const ushort* __restrict__ hI,
                         const int* __restrict__ pA, const int* __restrict__ cA,
                         const int* __restrict__ pB, const int* __restrict__ cB,
                         const int* __restrict__ pC, const int* __restrict__ cC,
                         ushort* __restrict__ sA, ushort* __restrict__ sB,
                         ushort* __restrict__ sC) {
    const int SEG = MPAD * 16 / 256;   // 6256 blocks per segment (16 lanes/half-row)
    int seg = blockIdx.x / SEG, lb = blockIdx.x % SEG;
    int dir = seg % 3, half = seg / 3;
    const ushort* x; const int* ptr; const int* col; ushort* out;
    if (dir == 0)      { x = hU; ptr = pA; col = cA; out = sA; }
    else if (dir == 1) { x = hI; ptr = pB; col = cB; out = sB; }
    else               { x = hI; ptr = pC; col = cC; out = sC; }
    int g = lb * 256 + threadIdx.x;
    int node = g >> 4, l = g & 15;
    if (node >= MPAD) return;
    int doff = half * 128 + l * 8;
    size_t ob = (size_t)node * 256 + doff;
    if (node >= NN) { *(uint4*)(out + ob) = make_uint4(0,0,0,0); return; }
    const ushort* xb = x + doff;
    int p0 = ptr[node], p1 = ptr[node + 1];
    float a[8] = {0.f,0.f,0.f,0.f,0.f,0.f,0.f,0.f};
    int e = p0;
    for (; e + 4 <= p1; e += 4) {
        int c0 = col[e], c1 = col[e+1], c2 = col[e+2], c3 = col[e+3];
        H8 v0, v1, v2, v3;
        v0.u = *(const uint4*)(xb + (size_t)c0 * 256);
        v1.u = *(const uint4*)(xb + (size_t)c1 * 256);
        v2.u = *(const uint4*)(xb + (size_t)c2 * 256);
        v3.u = *(const uint4*)(xb + (size_t)c3 * 256);
        #pragma unroll
        for (int k = 0; k < 8; k++) a[k] += (float)v0.h[k];
        #pragma unroll
        for (int k = 0; k < 8; k++) a[k] += (float)v1.h[k];
        #pragma unroll
        for (int k = 0; k < 8; k++) a[k] += (float)v2.h[k];
        #pragma unroll
        for (int k = 0; k < 8; k++) a[k] += (float)v3.h[k];
    }
    for (; e < p1; ++e) {
        H8 v; v.u = *(const uint4*)(xb + (size_t)col[e] * 256);
        #pragma unroll
        for (int k = 0; k < 8; k++) a[k] += (float)v.h[k];
    }
    float inv = (p1 > p0) ? 1.0f / (float)(p1 - p0) : 0.0f;
    H8 r;
    #pragma unroll
    for (int k = 0; k < 8; k++) r.h[k] = (_Float16)(a[k] * inv);
    *(uint4*)(out + ob) = r.u;
}

// ---------------------------------------------------------------------------
// fp16 MFMA GEMM, up to 3 fused parts, 2 problems per dispatch (blockIdx.z).
// Tile 128(M) x 256(full N), BK=64, 512 thr / 8 waves (2x4), wave tile 64x64
// (per-wave code identical to the verified round-7 kernel). A panel read
// ONCE per row-tile -> halves A HBM traffic vs round-8.
// Single-buffered LDS (48 KB), 2-barrier K-loop (proven structure).
// ---------------------------------------------------------------------------
struct GP {
    const ushort *A0, *W0, *A1, *W1, *A2, *W2;
    int ksh0, ksh1, ksh2;
    int c1, c2, S;
};

__global__ __launch_bounds__(512)
void gemm2x(GP Pa, const float* b0a, const float* b1a, float* Cfa, ushort* Cha, int fla,
            GP Pb, const float* b0b, const float* b1b, float* Cfb, ushort* Chb, int flb) {
    GP P; const float *b0, *b1; float* Cf; ushort* Ch; int flags;
    if (blockIdx.z == 0) { P = Pa; b0 = b0a; b1 = b1a; Cf = Cfa; Ch = Cha; flags = fla; }
    else                 { P = Pb; b0 = b0b; b1 = b1b; Cf = Cfb; Ch = Chb; flags = flb; }

    __shared__ ushort sA[128 * 64];   // 16 KB
    __shared__ ushort sW[256 * 64];   // 32 KB
    const int tid = threadIdx.x;
    const int m0 = blockIdx.x * 128;
    const int lane = tid & 63, w = tid >> 6;
    const int wr = (w >> 2) * 64, wc = (w & 3) * 64;   // 2x4 wave grid over 128x256
    const int fcol = lane & 15, fq = lane >> 4;
    const int srow = tid >> 3, sc = tid & 7;           // 64 rows / issue at 512 thr

    f32x4 acc[4][4];
    #pragma unroll
    for (int i = 0; i < 4; i++)
        #pragma unroll
        for (int j = 0; j < 4; j++) acc[i][j] = (f32x4){0.f,0.f,0.f,0.f};

    #pragma unroll 1
    for (int t = 0; t < P.S; ++t) {
        int p = (t >= P.c1) + (t >= P.c2);
        const ushort* A = (p == 2) ? P.A2 : (p == 1) ? P.A1 : P.A0;
        const ushort* W = (p == 2) ? P.W2 : (p == 1) ? P.W1 : P.W0;
        int ksh  = (p == 2) ? P.ksh2 : (p == 1) ? P.ksh1 : P.ksh0;
        int base = (p == 2) ? P.c2 : (p == 1) ? P.c1 : 0;
        int k0 = (t - base) << 6;

        // A tile: 128 rows -> 2 issues; W tile: 256 rows -> 4 issues
        #pragma unroll
        for (int ii = 0; ii < 2; ++ii) {
            int row = ii * 64 + srow;
            int q = sc ^ (row & 7);
            const ushort* srcA = A + (((size_t)(m0 + row)) << ksh) + k0 + q * 8;
            __builtin_amdgcn_global_load_lds((g_uint*)srcA,
                (lds_uint*)(sA + row * 64 + sc * 8), 16, 0, 0);
        }
        #pragma unroll
        for (int ii = 0; ii < 4; ++ii) {
            int row = ii * 64 + srow;
            int q = sc ^ (row & 7);
            const ushort* srcW = W + (((size_t)row) << ksh) + k0 + q * 8;
            __builtin_amdgcn_global_load_lds((g_uint*)srcW,
                (lds_uint*)(sW + row * 64 + sc * 8), 16, 0, 0);
        }
        __syncthreads();   // drain staging

        #pragma unroll
        for (int kk = 0; kk < 2; ++kk) {
            f16x8 a[4], b[4];
            #pragma unroll
            for (int i = 0; i < 4; ++i) {
                int ra = wr + i * 16 + fcol;
                int s = (fq + kk * 4) ^ (ra & 7);
                a[i] = *(const f16x8*)(sA + ra * 64 + s * 8);
            }
            #pragma unroll
            for (int j = 0; j < 4; ++j) {
                int rw = wc + j * 16 + fcol;
                int s = (fq + kk * 4) ^ (rw & 7);
                b[j] = *(const f16x8*)(sW + rw * 64 + s * 8);
            }
            #pragma unroll
            for (int i = 0; i < 4; ++i)
                #pragma unroll
                for (int j = 0; j < 4; ++j)
                    acc[i][j] = __builtin_amdgcn_mfma_f32_16x16x32_f16(a[i], b[j], acc[i][j], 0, 0, 0);
        }
        __syncthreads();   // protect buffer reuse
    }

    const bool relu = flags & F_RELU;
    float bb[4];
    #pragma unroll
    for (int j = 0; j < 4; ++j) {
        int cg = wc + j * 16 + fcol;
        float v = 0.f;
        if (b0) v += b0[cg];
        if (b1) v += b1[cg];
        bb[j] = v;
    }
    #pragma unroll
    for (int i = 0; i < 4; ++i) {
        #pragma unroll
        for (int r = 0; r < 4; ++r) {
            int gm = m0 + wr + i * 16 + fq * 4 + r;
            if (gm >= NN) continue;
            size_t rowb = (size_t)gm * 256;
            #pragma unroll
            for (int j = 0; j < 4; ++j) {
                size_t idx = rowb + wc + j * 16 + fcol;
                float v = acc[i][j][r] + bb[j];
                if (relu) v = fmaxf(v, 0.f);
                if (Ch) Ch[idx] = f2h(v);
                else    Cf[idx] = v;
            }
        }
    }
}

// ---------------------------------------------------------------------------
extern "C" void kernel_launch(void* const* d_in, const int* in_sizes, int n_in,
                              void* d_out, int out_size, void* d_ws, size_t ws_size,
                              hipStream_t stream) {
    const float* x_user = (const float*)d_in[0];
    const float* x_item = (const float*)d_in[1];
    const int* src_rev  = (const int*)d_in[2];
    const int* dst_rev  = (const int*)d_in[3];
    const int* src_ab   = (const int*)d_in[4];
    const int* dst_ab   = (const int*)d_in[5];
    const float* Wl1_rev  = (const float*)d_in[6];
    const float* Wr1_rev  = (const float*)d_in[7];
    const float* b1_rev   = (const float*)d_in[8];
    const float* Wl1_rrev = (const float*)d_in[9];
    const float* Wr1_rrev = (const float*)d_in[10];
    const float* b1_rrev  = (const float*)d_in[11];
    const float* Wl1_ab   = (const float*)d_in[12];
    const float* Wr1_ab   = (const float*)d_in[13];
    const float* b1_ab    = (const float*)d_in[14];
    const float* Wl2_rev  = (const float*)d_in[15];
    const float* Wr2_rev  = (const float*)d_in[16];
    const float* b2_rev   = (const float*)d_in[17];
    const float* Wl2_rrev = (const float*)d_in[18];
    const float* Wr2_rrev = (const float*)d_in[19];
    const float* b2_rrev  = (const float*)d_in[20];
    const float* Wl2_ab   = (const float*)d_in[21];
    const float* Wr2_ab   = (const float*)d_in[22];
    const float* b2_ab    = (const float*)d_in[23];

    float* o_user = (float*)d_out;
    float* o_item = (float*)d_out + (size_t)NN * 256;

    char* ws = (char*)d_ws;
    size_t off = 0;
    auto alloc = [&](size_t bytes) -> void* {
        void* p = ws + off;
        off += (bytes + 255) & ~(size_t)255;
        return p;
    };
    const size_t P256 = (size_t)MPAD * 256 * 2;
    const size_t P128 = (size_t)MPAD * 128 * 2;
    ushort* xu     = (ushort*)alloc(P128);
    ushort* xi     = (ushort*)alloc(P128);
    ushort* slabA  = (ushort*)alloc(P128);
    ushort* slabB  = (ushort*)alloc(P128);
    ushort* slabC  = (ushort*)alloc(P128);
    ushort* hI     = (ushort*)alloc(P256);
    ushort* hU     = (ushort*)alloc(P256);
    ushort* s2A    = (ushort*)alloc(P256);
    ushort* s2B    = (ushort*)alloc(P256);
    ushort* s2C    = (ushort*)alloc(P256);
    const size_t W1SZ = 128 * 256 * 2, W2SZ = 256 * 256 * 2;
    ushort* wt_l1rev  = (ushort*)alloc(W1SZ);
    ushort* wt_l1ab   = (ushort*)alloc(W1SZ);
    ushort* wt_l1rrev = (ushort*)alloc(W1SZ);
    ushort* wt_r1c    = (ushort*)alloc(W1SZ);
    ushort* wt_r1rrev = (ushort*)alloc(W1SZ);
    ushort* wt_l2rev  = (ushort*)alloc(W2SZ);
    ushort* wt_l2ab   = (ushort*)alloc(W2SZ);
    ushort* wt_l2rrev = (ushort*)alloc(W2SZ);
    ushort* wt_r2c    = (ushort*)alloc(W2SZ);
    ushort* wt_r2rrev = (ushort*)alloc(W2SZ);
    int* ptrA = (int*)alloc((NN + 1) * 4);
    int* ptrB = (int*)alloc((NN + 1) * 4);
    int* ptrC = (int*)alloc((NN + 1) * 4);
    int* colA = (int*)alloc((size_t)ER_ * 4);
    int* colB = (int*)alloc((size_t)EA_ * 4);
    int* colC = (int*)alloc((size_t)ER_ * 4);
    int* cnt3 = (int*)alloc((size_t)3 * NN * 4);   // counts, then reused as cursors
    int* part  = (int*)alloc(3 * NCH * 4);
    int* choff = (int*)alloc(3 * NCH * 4);

    const int TPB = 256;
    const int NE3 = ER_ + EA_ + ER_;
    dim3 e3grid((NE3 + TPB - 1) / TPB);

    // ---- CSR build ----
    hipMemsetAsync(cnt3, 0, (size_t)3 * NN * 4, stream);
    count3<<<e3grid, TPB, 0, stream>>>(dst_rev, dst_ab, src_rev, cnt3);
    scan_part<<<3 * NCH, TPB, 0, stream>>>(cnt3, part);
    scan_off<<<1, 64, 0, stream>>>(part, choff, ptrA, ptrB, ptrC);
    scan_apply<<<3 * NCH, TPB, 0, stream>>>(cnt3, choff, ptrA, ptrB, ptrC);
    hipMemsetAsync(cnt3, 0, (size_t)3 * NN * 4, stream);
    fill3<<<e3grid, TPB, 0, stream>>>(dst_rev, src_rev, dst_ab, src_ab,
                                      ptrA, ptrB, ptrC, cnt3, colA, colB, colC);

    // ---- fused prep (cvt x2 + wprep x10) ----
    PrepArgs PA;
    PA.xsrc[0] = x_user; PA.xdst[0] = xu;
    PA.xsrc[1] = x_item; PA.xdst[1] = xi;
    const float* W0s[10] = {Wl1_rev, Wl1_ab, Wl1_rrev, Wr1_rev, Wr1_rrev,
                            Wl2_rev, Wl2_ab, Wl2_rrev, Wr2_rev, Wr2_rrev};
    const float* W1s[10] = {nullptr, nullptr, nullptr, Wr1_ab, nullptr,
                            nullptr, nullptr, nullptr, Wr2_ab, nullptr};
    ushort* Ts[10] = {wt_l1rev, wt_l1ab, wt_l1rrev, wt_r1c, wt_r1rrev,
                      wt_l2rev, wt_l2ab, wt_l2rrev, wt_r2c, wt_r2rrev};
    for (int i = 0; i < 10; i++) { PA.W0[i] = W0s[i]; PA.W1[i] = W1s[i]; PA.T[i] = Ts[i]; }
    const long CVB = (long)MPAD * 128 / 8 / 256;          // 6256
    const long WPB = (5 * 32768 + 5 * 65536 + 255) / 256; // 1920
    prep_all<<<(int)(2 * CVB + WPB), TPB, 0, stream>>>(PA);

    dim3 ggrid(MPAD / 128, 1, 2);

    auto mkGP = [&](const ushort* a0, const ushort* w0, int K0,
                    const ushort* a1, const ushort* w1, int K1,
                    const ushort* a2, const ushort* w2, int K2) {
        GP P;
        P.A0 = a0; P.W0 = w0;
        P.A1 = a1 ? a1 : a0; P.W1 = w1 ? w1 : w0;
        P.A2 = a2 ? a2 : a0; P.W2 = w2 ? w2 : w0;
        P.ksh0 = (K0 == 256) ? 8 : 7;
        P.ksh1 = (K1 == 256) ? 8 : 7;
        P.ksh2 = (K2 == 256) ? 8 : 7;
        P.c1 = K0 >> 6; P.c2 = P.c1 + (K1 >> 6); P.S = P.c2 + (K2 >> 6);
        return P;
    };

    // ---- layer 1 ----
    agg3_128<<<6 * (MPAD * 8 / 256), TPB, 0, stream>>>(xu, xi, ptrA, colA, ptrB, colB,
                                                       ptrC, colC, slabA, slabB, slabC);
    {
        GP P0 = mkGP(slabA, wt_l1rev, 128, slabB, wt_l1ab, 128, xi, wt_r1c, 128);
        GP P1 = mkGP(slabC, wt_l1rrev, 128, xu, wt_r1rrev, 128, nullptr, nullptr, 0);
        gemm2x<<<ggrid, 512, 0, stream>>>(P0, b1_rev, b1_ab, nullptr, hI, F_RELU,
                                          P1, b1_rrev, nullptr, nullptr, hU, F_RELU);
    }

    // ---- layer 2 ----
    agg3_256<<<6 * (MPAD * 16 / 256), TPB, 0, stream>>>(hU, hI, ptrA, colA, ptrB, colB,
                                                        ptrC, colC, s2A, s2B, s2C);
    {
        GP P0 = mkGP(s2A, wt_l2rev, 256, s2B, wt_l2ab, 256, hI, wt_r2c, 256);
        GP P1 = mkGP(s2C, wt_l2rrev, 256, hU, wt_r2rrev, 256, nullptr, nullptr, 0);
        gemm2x<<<ggrid, 512, 0, stream>>>(P0, b2_rev, b2_ab, o_item, nullptr, 0,
                                          P1, b2_rrev, nullptr, o_user, nullptr, 0);
    }
}